// Round 1
// baseline (992.969 us; speedup 1.0000x reference)
//
#include <hip/hip_runtime.h>
#include <hip/hip_bf16.h>
#include <stdint.h>

// Problem constants
#define BB 8
#define NN 2048
#define DD 768
#define HH 12
#define HD 64
#define ND3 2304           // 3*D
#define TOK (BB*NN)        // 16384 rows
#define SCALE 0.125f       // HD^-0.5

typedef __bf16 bf16x8 __attribute__((ext_vector_type(8)));
typedef float  f32x4  __attribute__((ext_vector_type(4)));

__device__ __forceinline__ unsigned short f2bf(float f) {
    union { float f; unsigned u; } v; v.f = f;
    unsigned r = v.u + 0x7FFF + ((v.u >> 16) & 1);   // RNE
    return (unsigned short)(r >> 16);
}

// ---------------------------------------------------------------- prep kernels
__global__ __launch_bounds__(256) void f32_to_bf16_vec(const float* __restrict__ in,
                                                       unsigned short* __restrict__ out, int n4) {
    int i = blockIdx.x * 256 + threadIdx.x;
    if (i < n4) {
        float4 v = reinterpret_cast<const float4*>(in)[i];
        ushort4 o;
        o.x = f2bf(v.x); o.y = f2bf(v.y); o.z = f2bf(v.z); o.w = f2bf(v.w);
        reinterpret_cast<ushort4*>(out)[i] = o;
    }
}

// in[R][C] f32  ->  out[C][R] bf16   (write-coalesced)
__global__ __launch_bounds__(256) void transpose_bf16(const float* __restrict__ in,
                                                      unsigned short* __restrict__ out,
                                                      int R, int C) {
    int idx = blockIdx.x * 256 + threadIdx.x;
    if (idx < R * C) {
        int ci = idx / R;
        int r  = idx - ci * R;
        out[(size_t)ci * R + r] = f2bf(in[(size_t)r * C + ci]);
    }
}

// ---------------------------------------------------------------- QKV GEMM
// C[16384,2304] = xb[16384,768] @ W_qkv + b_qkv ; scatter to q/k/vt (bf16)
// block = 256 thr (4 waves, 2x2 of 64x64 wave tiles -> 128x128 block tile)
// grid = (2304/128=18, 16384/128=128)
__global__ __launch_bounds__(256) void qkv_gemm(const unsigned short* __restrict__ xb,
                                                const unsigned short* __restrict__ wt,   // [2304][768] = W^T
                                                const float* __restrict__ bias,          // [2304]
                                                unsigned short* __restrict__ qb,         // [B,H,N,64]
                                                unsigned short* __restrict__ kb,         // [B,H,N,64]
                                                unsigned short* __restrict__ vt) {       // [B,H,64,N]
    const int tid  = threadIdx.x;
    const int wave = tid >> 6;
    const int lane = tid & 63;
    const int qd   = lane >> 4;       // quad 0..3
    const int c    = lane & 15;
    const int m0 = blockIdx.y * 128 + (wave >> 1) * 64;
    const int n0 = blockIdx.x * 128 + (wave & 1) * 64;

    f32x4 acc[4][4] = {};
    for (int k0 = 0; k0 < DD; k0 += 32) {
        bf16x8 a[4], b[4];
        #pragma unroll
        for (int i = 0; i < 4; ++i)
            a[i] = *reinterpret_cast<const bf16x8*>(xb + (size_t)(m0 + i * 16 + c) * DD + k0 + qd * 8);
        #pragma unroll
        for (int j = 0; j < 4; ++j)
            b[j] = *reinterpret_cast<const bf16x8*>(wt + (size_t)(n0 + j * 16 + c) * DD + k0 + qd * 8);
        #pragma unroll
        for (int i = 0; i < 4; ++i)
            #pragma unroll
            for (int j = 0; j < 4; ++j)
                acc[i][j] = __builtin_amdgcn_mfma_f32_16x16x32_bf16(a[i], b[j], acc[i][j], 0, 0, 0);
    }

    #pragma unroll
    for (int i = 0; i < 4; ++i)
        #pragma unroll
        for (int j = 0; j < 4; ++j)
            #pragma unroll
            for (int r = 0; r < 4; ++r) {
                int row = m0 + i * 16 + qd * 4 + r;
                int col = n0 + j * 16 + c;
                float v = acc[i][j][r] + bias[col];
                unsigned short bv = f2bf(v);
                int t  = col / DD;
                int cc = col - t * DD;
                int h  = cc >> 6;
                int d  = cc & 63;
                int bi = row >> 11;
                int n  = row & (NN - 1);
                size_t bh = (size_t)(bi * HH + h);
                if (t == 0)      qb[(bh * NN + n) * HD + d] = bv;
                else if (t == 1) kb[(bh * NN + n) * HD + d] = bv;
                else             vt[(bh * HD + d) * NN + n] = bv;
            }
}

// ---------------------------------------------------------------- flash attention
// grid = (B*H=96, N/128=16); block = 256 (4 waves x 32 queries)
__global__ __launch_bounds__(256) void attn_kernel(const unsigned short* __restrict__ qb,
                                                   const unsigned short* __restrict__ kb,
                                                   const unsigned short* __restrict__ vt,
                                                   unsigned short* __restrict__ ao) {   // [B,N,D] bf16
    const int bh   = blockIdx.x;
    const int tid  = threadIdx.x;
    const int wave = tid >> 6;
    const int lane = tid & 63;
    const int qd   = lane >> 4;
    const int c    = lane & 15;
    const int q0   = blockIdx.y * 128 + wave * 32;

    const unsigned short* Qp = qb + (size_t)bh * NN * HD;
    const unsigned short* Kp = kb + (size_t)bh * NN * HD;
    const unsigned short* Vp = vt + (size_t)bh * HD * NN;

    __shared__ unsigned short Ps[4][32][40];   // per-wave P tile, padded (2-way bank alias only)

    // persistent Q fragments: 2 m-tiles x 2 k-steps
    bf16x8 aq[2][2];
    #pragma unroll
    for (int mi = 0; mi < 2; ++mi)
        #pragma unroll
        for (int ks = 0; ks < 2; ++ks)
            aq[mi][ks] = *reinterpret_cast<const bf16x8*>(
                Qp + (size_t)(q0 + mi * 16 + c) * HD + ks * 32 + qd * 8);

    f32x4 o[2][4] = {};
    float m_i[2][4], l_i[2][4];
    #pragma unroll
    for (int mi = 0; mi < 2; ++mi)
        #pragma unroll
        for (int r = 0; r < 4; ++r) { m_i[mi][r] = -INFINITY; l_i[mi][r] = 0.f; }

    #pragma unroll 1
    for (int kt = 0; kt < NN; kt += 32) {
        // ---- S = Q @ K^T (16x16x32 MFMA, k over d=64)
        f32x4 s[2][2] = {};
        bf16x8 bk[2][2];
        #pragma unroll
        for (int nt = 0; nt < 2; ++nt)
            #pragma unroll
            for (int ks = 0; ks < 2; ++ks)
                bk[nt][ks] = *reinterpret_cast<const bf16x8*>(
                    Kp + (size_t)(kt + nt * 16 + c) * HD + ks * 32 + qd * 8);
        #pragma unroll
        for (int mi = 0; mi < 2; ++mi)
            #pragma unroll
            for (int nt = 0; nt < 2; ++nt)
                #pragma unroll
                for (int ks = 0; ks < 2; ++ks)
                    s[mi][nt] = __builtin_amdgcn_mfma_f32_16x16x32_bf16(aq[mi][ks], bk[nt][ks], s[mi][nt], 0, 0, 0);

        // ---- online softmax (rows = qd*4+r, cols spread over 16 lanes x 2 regs)
        #pragma unroll
        for (int mi = 0; mi < 2; ++mi)
            #pragma unroll
            for (int r = 0; r < 4; ++r) {
                float s0 = s[mi][0][r] * SCALE;
                float s1 = s[mi][1][r] * SCALE;
                float mx = fmaxf(s0, s1);
                #pragma unroll
                for (int off = 1; off < 16; off <<= 1)
                    mx = fmaxf(mx, __shfl_xor(mx, off, 16));
                float mnew  = fmaxf(m_i[mi][r], mx);
                float alpha = __expf(m_i[mi][r] - mnew);
                m_i[mi][r]  = mnew;
                float p0 = __expf(s0 - mnew);
                float p1 = __expf(s1 - mnew);
                s[mi][0][r] = p0;
                s[mi][1][r] = p1;
                float rs = p0 + p1;
                #pragma unroll
                for (int off = 1; off < 16; off <<= 1)
                    rs += __shfl_xor(rs, off, 16);
                l_i[mi][r] = l_i[mi][r] * alpha + rs;
                #pragma unroll
                for (int nv = 0; nv < 4; ++nv)
                    o[mi][nv][r] *= alpha;
            }

        // ---- P (C-layout) -> LDS -> A-operand layout
        #pragma unroll
        for (int mi = 0; mi < 2; ++mi)
            #pragma unroll
            for (int nt = 0; nt < 2; ++nt)
                #pragma unroll
                for (int r = 0; r < 4; ++r)
                    Ps[wave][mi * 16 + qd * 4 + r][nt * 16 + c] = f2bf(s[mi][nt][r]);
        __syncthreads();
        bf16x8 ap[2];
        #pragma unroll
        for (int mi = 0; mi < 2; ++mi)
            ap[mi] = *reinterpret_cast<const bf16x8*>(&Ps[wave][mi * 16 + c][qd * 8]);

        // ---- O += P @ V   (V^T layout -> contiguous B frags)
        bf16x8 bv[4];
        #pragma unroll
        for (int nv = 0; nv < 4; ++nv)
            bv[nv] = *reinterpret_cast<const bf16x8*>(
                Vp + (size_t)(nv * 16 + c) * NN + kt + qd * 8);
        #pragma unroll
        for (int mi = 0; mi < 2; ++mi)
            #pragma unroll
            for (int nv = 0; nv < 4; ++nv)
                o[mi][nv] = __builtin_amdgcn_mfma_f32_16x16x32_bf16(ap[mi], bv[nv], o[mi][nv], 0, 0, 0);
        __syncthreads();
    }

    // ---- epilogue: O / l -> attnout [B,N,D] bf16
    const int bi = bh / HH;
    const int h  = bh - bi * HH;
    #pragma unroll
    for (int mi = 0; mi < 2; ++mi)
        #pragma unroll
        for (int r = 0; r < 4; ++r) {
            float inv = 1.0f / l_i[mi][r];
            int n = q0 + mi * 16 + qd * 4 + r;
            size_t base = ((size_t)bi * NN + n) * DD + h * HD;
            #pragma unroll
            for (int nv = 0; nv < 4; ++nv)
                ao[base + nv * 16 + c] = f2bf(o[mi][nv][r] * inv);
        }
}

// ---------------------------------------------------------------- out projection
// out[16384,768] = ao[16384,768] @ W_out + b_out   (f32 output)
// grid = (768/128=6, 16384/128=128)
__global__ __launch_bounds__(256) void out_gemm(const unsigned short* __restrict__ ab,
                                                const unsigned short* __restrict__ wt,   // [768][768] = W_out^T
                                                const float* __restrict__ bias,
                                                float* __restrict__ out) {
    const int tid  = threadIdx.x;
    const int wave = tid >> 6;
    const int lane = tid & 63;
    const int qd   = lane >> 4;
    const int c    = lane & 15;
    const int m0 = blockIdx.y * 128 + (wave >> 1) * 64;
    const int n0 = blockIdx.x * 128 + (wave & 1) * 64;

    f32x4 acc[4][4] = {};
    for (int k0 = 0; k0 < DD; k0 += 32) {
        bf16x8 a[4], b[4];
        #pragma unroll
        for (int i = 0; i < 4; ++i)
            a[i] = *reinterpret_cast<const bf16x8*>(ab + (size_t)(m0 + i * 16 + c) * DD + k0 + qd * 8);
        #pragma unroll
        for (int j = 0; j < 4; ++j)
            b[j] = *reinterpret_cast<const bf16x8*>(wt + (size_t)(n0 + j * 16 + c) * DD + k0 + qd * 8);
        #pragma unroll
        for (int i = 0; i < 4; ++i)
            #pragma unroll
            for (int j = 0; j < 4; ++j)
                acc[i][j] = __builtin_amdgcn_mfma_f32_16x16x32_bf16(a[i], b[j], acc[i][j], 0, 0, 0);
    }

    #pragma unroll
    for (int i = 0; i < 4; ++i)
        #pragma unroll
        for (int j = 0; j < 4; ++j)
            #pragma unroll
            for (int r = 0; r < 4; ++r) {
                int row = m0 + i * 16 + qd * 4 + r;
                int col = n0 + j * 16 + c;
                out[(size_t)row * DD + col] = acc[i][j][r] + bias[col];
            }
}

// ---------------------------------------------------------------- launch
extern "C" void kernel_launch(void* const* d_in, const int* in_sizes, int n_in,
                              void* d_out, int out_size, void* d_ws, size_t ws_size,
                              hipStream_t stream) {
    const float* x     = (const float*)d_in[0];   // [8,2048,768]
    const float* W_qkv = (const float*)d_in[1];   // [768,2304]
    const float* b_qkv = (const float*)d_in[2];   // [2304]
    const float* W_out = (const float*)d_in[3];   // [768,768]
    const float* b_out = (const float*)d_in[4];   // [768]
    float* out = (float*)d_out;                   // [8,2048,768]

    // workspace layout (bytes), all 256-aligned
    char* ws = (char*)d_ws;
    const size_t SZ_X   = (size_t)TOK * DD * 2;        // 25.2 MB bf16 x
    const size_t SZ_WQ  = (size_t)ND3 * DD * 2;        //  3.5 MB W_qkv^T
    const size_t SZ_WO  = (size_t)DD * DD * 2;         //  1.2 MB W_out^T
    const size_t SZ_QKV = (size_t)TOK * DD * 2;        // 25.2 MB each (q / k / vt / ao)
    unsigned short* xb  = (unsigned short*)(ws);
    unsigned short* wtq = (unsigned short*)(ws + SZ_X);
    unsigned short* wto = (unsigned short*)(ws + SZ_X + SZ_WQ);
    unsigned short* qb  = (unsigned short*)(ws + SZ_X + SZ_WQ + SZ_WO);
    unsigned short* kb  = (unsigned short*)(ws + SZ_X + SZ_WQ + SZ_WO + SZ_QKV);
    unsigned short* vtb = (unsigned short*)(ws + SZ_X + SZ_WQ + SZ_WO + 2 * SZ_QKV);
    unsigned short* ao  = (unsigned short*)(ws + SZ_X + SZ_WQ + SZ_WO + 3 * SZ_QKV);
    // total ~130.5 MB required of ws_size

    // prep
    {
        int n4 = TOK * DD / 4;
        f32_to_bf16_vec<<<(n4 + 255) / 256, 256, 0, stream>>>(x, xb, n4);
        int nq = DD * ND3;
        transpose_bf16<<<(nq + 255) / 256, 256, 0, stream>>>(W_qkv, wtq, DD, ND3);
        int no = DD * DD;
        transpose_bf16<<<(no + 255) / 256, 256, 0, stream>>>(W_out, wto, DD, DD);
    }
    // qkv projection + scatter
    qkv_gemm<<<dim3(ND3 / 128, TOK / 128), 256, 0, stream>>>(xb, wtq, b_qkv, qb, kb, vtb);
    // flash attention
    attn_kernel<<<dim3(BB * HH, NN / 128), 256, 0, stream>>>(qb, kb, vtb, ao);
    // output projection
    out_gemm<<<dim3(DD / 128, TOK / 128), 256, 0, stream>>>(ao, wto, b_out, out);
}

// Round 2
// 809.330 us; speedup vs baseline: 1.2269x; 1.2269x over previous
//
#include <hip/hip_runtime.h>
#include <hip/hip_bf16.h>
#include <stdint.h>

// Problem constants
#define BB 8
#define NN 2048
#define DD 768
#define HH 12
#define HD 64
#define ND3 2304           // 3*D
#define TOK (BB*NN)        // 16384 rows
// SCALE * log2(e) folded into q at qkv epilogue
#define QSC 0.18033688011112042f

typedef __bf16 bf16x8 __attribute__((ext_vector_type(8)));
typedef float  f32x4  __attribute__((ext_vector_type(4)));

__device__ __forceinline__ unsigned short f2bf(float f) {
    union { float f; unsigned u; } v; v.f = f;
    unsigned r = v.u + 0x7FFF + ((v.u >> 16) & 1);   // RNE
    return (unsigned short)(r >> 16);
}

// ---------------------------------------------------------------- prep kernels
__global__ __launch_bounds__(256) void f32_to_bf16_vec(const float* __restrict__ in,
                                                       unsigned short* __restrict__ out, int n4) {
    int i = blockIdx.x * 256 + threadIdx.x;
    if (i < n4) {
        float4 v = reinterpret_cast<const float4*>(in)[i];
        ushort4 o;
        o.x = f2bf(v.x); o.y = f2bf(v.y); o.z = f2bf(v.z); o.w = f2bf(v.w);
        reinterpret_cast<ushort4*>(out)[i] = o;
    }
}

// in[R][C] f32  ->  out[C][R] bf16   (write-coalesced)
__global__ __launch_bounds__(256) void transpose_bf16(const float* __restrict__ in,
                                                      unsigned short* __restrict__ out,
                                                      int R, int C) {
    int idx = blockIdx.x * 256 + threadIdx.x;
    if (idx < R * C) {
        int ci = idx / R;
        int r  = idx - ci * R;
        out[(size_t)ci * R + r] = f2bf(in[(size_t)r * C + ci]);
    }
}

// ---------------------------------------------------------------- QKV GEMM
// C[16384,2304] = xb[16384,768] @ W_qkv + b_qkv ; scatter to q/k/vt (bf16)
// q output is pre-scaled by QSC (attention runs in exp2 domain).
__global__ __launch_bounds__(256) void qkv_gemm(const unsigned short* __restrict__ xb,
                                                const unsigned short* __restrict__ wt,   // [2304][768] = W^T
                                                const float* __restrict__ bias,          // [2304]
                                                unsigned short* __restrict__ qb,         // [B,H,N,64]
                                                unsigned short* __restrict__ kb,         // [B,H,N,64]
                                                unsigned short* __restrict__ vt) {       // [B,H,64,N]
    const int tid  = threadIdx.x;
    const int wave = tid >> 6;
    const int lane = tid & 63;
    const int qd   = lane >> 4;       // quad 0..3
    const int c    = lane & 15;
    const int m0 = blockIdx.y * 128 + (wave >> 1) * 64;
    const int n0 = blockIdx.x * 128 + (wave & 1) * 64;

    f32x4 acc[4][4] = {};
    for (int k0 = 0; k0 < DD; k0 += 32) {
        bf16x8 a[4], b[4];
        #pragma unroll
        for (int i = 0; i < 4; ++i)
            a[i] = *reinterpret_cast<const bf16x8*>(xb + (size_t)(m0 + i * 16 + c) * DD + k0 + qd * 8);
        #pragma unroll
        for (int j = 0; j < 4; ++j)
            b[j] = *reinterpret_cast<const bf16x8*>(wt + (size_t)(n0 + j * 16 + c) * DD + k0 + qd * 8);
        #pragma unroll
        for (int i = 0; i < 4; ++i)
            #pragma unroll
            for (int j = 0; j < 4; ++j)
                acc[i][j] = __builtin_amdgcn_mfma_f32_16x16x32_bf16(a[i], b[j], acc[i][j], 0, 0, 0);
    }

    #pragma unroll
    for (int i = 0; i < 4; ++i)
        #pragma unroll
        for (int j = 0; j < 4; ++j)
            #pragma unroll
            for (int r = 0; r < 4; ++r) {
                int row = m0 + i * 16 + qd * 4 + r;
                int col = n0 + j * 16 + c;
                float v = acc[i][j][r] + bias[col];
                int t  = col / DD;
                int cc = col - t * DD;
                int h  = cc >> 6;
                int d  = cc & 63;
                int bi = row >> 11;
                int n  = row & (NN - 1);
                size_t bh = (size_t)(bi * HH + h);
                if (t == 0)      qb[(bh * NN + n) * HD + d] = f2bf(v * QSC);
                else if (t == 1) kb[(bh * NN + n) * HD + d] = f2bf(v);
                else             vt[(bh * HD + d) * NN + n] = f2bf(v);
            }
}

// ---------------------------------------------------------------- flash attention
// Transposed-score design: S^T = K @ Q^T so the key reduction lives in regs.
// grid = (B*H=96, N/128=16); block = 256 (4 waves x 32 queries), 64-key tiles.
__global__ __launch_bounds__(256) void attn_kernel(const unsigned short* __restrict__ qb,
                                                   const unsigned short* __restrict__ kb,
                                                   const unsigned short* __restrict__ vt,
                                                   unsigned short* __restrict__ ao) {   // [B,N,D] bf16
    const int bh   = blockIdx.x;
    const int tid  = threadIdx.x;
    const int wave = tid >> 6;
    const int lane = tid & 63;
    const int qd   = lane >> 4;
    const int c    = lane & 15;
    const int q0   = blockIdx.y * 128 + wave * 32;

    const unsigned short* Qp = qb + (size_t)bh * NN * HD;
    const unsigned short* Kp = kb + (size_t)bh * NN * HD;
    const unsigned short* Vp = vt + (size_t)bh * HD * NN;

    // per-wave private P tile: [32 queries][64 keys], stride 80 for 16B-aligned rows
    __shared__ __align__(16) unsigned short Plds[4][32][80];
    unsigned short (*Pw)[80] = Plds[wave];

    // persistent Q fragments (B-operand): B[k=d][n=query]
    bf16x8 aq[2][2];
    #pragma unroll
    for (int mi = 0; mi < 2; ++mi)
        #pragma unroll
        for (int ks = 0; ks < 2; ++ks)
            aq[mi][ks] = *reinterpret_cast<const bf16x8*>(
                Qp + (size_t)(q0 + mi * 16 + c) * HD + ks * 32 + qd * 8);

    f32x4 o[2][4] = {};
    float m_i[2] = {-INFINITY, -INFINITY};
    float l_i[2] = {0.f, 0.f};

    #pragma unroll 1
    for (int kt = 0; kt < NN; kt += 64) {
        // ---- S^T = K @ Q^T : A = K frags (m=key), B = Q frags (n=query)
        bf16x8 ak[4][2];
        #pragma unroll
        for (int nt = 0; nt < 4; ++nt)
            #pragma unroll
            for (int ks = 0; ks < 2; ++ks)
                ak[nt][ks] = *reinterpret_cast<const bf16x8*>(
                    Kp + (size_t)(kt + nt * 16 + c) * HD + ks * 32 + qd * 8);

        f32x4 s[4][2] = {};   // [nt key-tile][mi query-tile]; C: col=query, row=key
        #pragma unroll
        for (int ks = 0; ks < 2; ++ks)
            #pragma unroll
            for (int nt = 0; nt < 4; ++nt)
                #pragma unroll
                for (int mi = 0; mi < 2; ++mi)
                    s[nt][mi] = __builtin_amdgcn_mfma_f32_16x16x32_bf16(ak[nt][ks], aq[mi][ks], s[nt][mi], 0, 0, 0);

        // ---- online softmax (exp2 domain; per lane: 16 keys of query mi*16+c)
        float alpha[2];
        #pragma unroll
        for (int mi = 0; mi < 2; ++mi) {
            float mx = s[0][mi][0];
            #pragma unroll
            for (int nt = 0; nt < 4; ++nt)
                #pragma unroll
                for (int r = 0; r < 4; ++r)
                    mx = fmaxf(mx, s[nt][mi][r]);
            mx = fmaxf(mx, __shfl_xor(mx, 16, 64));
            mx = fmaxf(mx, __shfl_xor(mx, 32, 64));
            float mnew = fmaxf(m_i[mi], mx);
            alpha[mi] = __builtin_amdgcn_exp2f(m_i[mi] - mnew);
            m_i[mi] = mnew;
            float rs = 0.f;
            #pragma unroll
            for (int nt = 0; nt < 4; ++nt)
                #pragma unroll
                for (int r = 0; r < 4; ++r) {
                    float p = __builtin_amdgcn_exp2f(s[nt][mi][r] - mnew);
                    s[nt][mi][r] = p;
                    rs += p;
                }
            rs += __shfl_xor(rs, 16, 64);
            rs += __shfl_xor(rs, 32, 64);
            l_i[mi] = l_i[mi] * alpha[mi] + rs;
        }

        // ---- O rescale: broadcast alpha from softmax layout (query=lane&15)
        //      into C-row layout (query row = qd*4+r)
        #pragma unroll
        for (int mi = 0; mi < 2; ++mi)
            #pragma unroll
            for (int r = 0; r < 4; ++r) {
                float ar = __shfl(alpha[mi], (lane & 48) | (qd * 4 + r), 64);
                #pragma unroll
                for (int nv = 0; nv < 4; ++nv)
                    o[mi][nv][r] *= ar;
            }

        // ---- P^T (key-major regs) -> LDS as P[q][k], packed b64 stores
        #pragma unroll
        for (int mi = 0; mi < 2; ++mi)
            #pragma unroll
            for (int nt = 0; nt < 4; ++nt) {
                unsigned u0 = __float_as_uint(s[nt][mi][0]) + 0x8000u;
                unsigned u1 = __float_as_uint(s[nt][mi][1]) + 0x8000u;
                unsigned u2 = __float_as_uint(s[nt][mi][2]) + 0x8000u;
                unsigned u3 = __float_as_uint(s[nt][mi][3]) + 0x8000u;
                uint2 dd;
                dd.x = __builtin_amdgcn_perm(u1, u0, 0x07060302u);
                dd.y = __builtin_amdgcn_perm(u3, u2, 0x07060302u);
                *reinterpret_cast<uint2*>(&Pw[mi * 16 + c][nt * 16 + qd * 4]) = dd;
            }
        asm volatile("s_waitcnt lgkmcnt(0)" ::: "memory");

        // ---- O += P @ V : A = P from LDS, B = V^T frags
        #pragma unroll
        for (int ks = 0; ks < 2; ++ks) {
            bf16x8 ap0 = *reinterpret_cast<const bf16x8*>(&Pw[c][ks * 32 + qd * 8]);
            bf16x8 ap1 = *reinterpret_cast<const bf16x8*>(&Pw[16 + c][ks * 32 + qd * 8]);
            #pragma unroll
            for (int nv = 0; nv < 4; ++nv) {
                bf16x8 bv = *reinterpret_cast<const bf16x8*>(
                    Vp + (size_t)(nv * 16 + c) * NN + kt + ks * 32 + qd * 8);
                o[0][nv] = __builtin_amdgcn_mfma_f32_16x16x32_bf16(ap0, bv, o[0][nv], 0, 0, 0);
                o[1][nv] = __builtin_amdgcn_mfma_f32_16x16x32_bf16(ap1, bv, o[1][nv], 0, 0, 0);
            }
        }
        asm volatile("" ::: "memory");   // keep next-iter LDS writes below these reads
    }

    // ---- epilogue: O / l -> attnout [B,N,D] bf16
    const int bi = bh / HH;
    const int h  = bh - bi * HH;
    #pragma unroll
    for (int mi = 0; mi < 2; ++mi) {
        float linv = 1.0f / l_i[mi];
        #pragma unroll
        for (int r = 0; r < 4; ++r) {
            float lr = __shfl(linv, (lane & 48) | (qd * 4 + r), 64);
            int n = q0 + mi * 16 + qd * 4 + r;
            size_t base = ((size_t)bi * NN + n) * DD + h * HD;
            #pragma unroll
            for (int nv = 0; nv < 4; ++nv)
                ao[base + nv * 16 + c] = f2bf(o[mi][nv][r] * lr);
        }
    }
}

// ---------------------------------------------------------------- out projection
// out[16384,768] = ao[16384,768] @ W_out + b_out   (f32 output)
__global__ __launch_bounds__(256) void out_gemm(const unsigned short* __restrict__ ab,
                                                const unsigned short* __restrict__ wt,   // [768][768] = W_out^T
                                                const float* __restrict__ bias,
                                                float* __restrict__ out) {
    const int tid  = threadIdx.x;
    const int wave = tid >> 6;
    const int lane = tid & 63;
    const int qd   = lane >> 4;
    const int c    = lane & 15;
    const int m0 = blockIdx.y * 128 + (wave >> 1) * 64;
    const int n0 = blockIdx.x * 128 + (wave & 1) * 64;

    f32x4 acc[4][4] = {};
    for (int k0 = 0; k0 < DD; k0 += 32) {
        bf16x8 a[4], b[4];
        #pragma unroll
        for (int i = 0; i < 4; ++i)
            a[i] = *reinterpret_cast<const bf16x8*>(ab + (size_t)(m0 + i * 16 + c) * DD + k0 + qd * 8);
        #pragma unroll
        for (int j = 0; j < 4; ++j)
            b[j] = *reinterpret_cast<const bf16x8*>(wt + (size_t)(n0 + j * 16 + c) * DD + k0 + qd * 8);
        #pragma unroll
        for (int i = 0; i < 4; ++i)
            #pragma unroll
            for (int j = 0; j < 4; ++j)
                acc[i][j] = __builtin_amdgcn_mfma_f32_16x16x32_bf16(a[i], b[j], acc[i][j], 0, 0, 0);
    }

    #pragma unroll
    for (int i = 0; i < 4; ++i)
        #pragma unroll
        for (int j = 0; j < 4; ++j)
            #pragma unroll
            for (int r = 0; r < 4; ++r) {
                int row = m0 + i * 16 + qd * 4 + r;
                int col = n0 + j * 16 + c;
                out[(size_t)row * DD + col] = acc[i][j][r] + bias[col];
            }
}

// ---------------------------------------------------------------- launch
extern "C" void kernel_launch(void* const* d_in, const int* in_sizes, int n_in,
                              void* d_out, int out_size, void* d_ws, size_t ws_size,
                              hipStream_t stream) {
    const float* x     = (const float*)d_in[0];   // [8,2048,768]
    const float* W_qkv = (const float*)d_in[1];   // [768,2304]
    const float* b_qkv = (const float*)d_in[2];   // [2304]
    const float* W_out = (const float*)d_in[3];   // [768,768]
    const float* b_out = (const float*)d_in[4];   // [768]
    float* out = (float*)d_out;                   // [8,2048,768]

    char* ws = (char*)d_ws;
    const size_t SZ_X   = (size_t)TOK * DD * 2;
    const size_t SZ_WQ  = (size_t)ND3 * DD * 2;
    const size_t SZ_WO  = (size_t)DD * DD * 2;
    const size_t SZ_QKV = (size_t)TOK * DD * 2;
    unsigned short* xb  = (unsigned short*)(ws);
    unsigned short* wtq = (unsigned short*)(ws + SZ_X);
    unsigned short* wto = (unsigned short*)(ws + SZ_X + SZ_WQ);
    unsigned short* qb  = (unsigned short*)(ws + SZ_X + SZ_WQ + SZ_WO);
    unsigned short* kb  = (unsigned short*)(ws + SZ_X + SZ_WQ + SZ_WO + SZ_QKV);
    unsigned short* vtb = (unsigned short*)(ws + SZ_X + SZ_WQ + SZ_WO + 2 * SZ_QKV);
    unsigned short* ao  = (unsigned short*)(ws + SZ_X + SZ_WQ + SZ_WO + 3 * SZ_QKV);

    {
        int n4 = TOK * DD / 4;
        f32_to_bf16_vec<<<(n4 + 255) / 256, 256, 0, stream>>>(x, xb, n4);
        int nq = DD * ND3;
        transpose_bf16<<<(nq + 255) / 256, 256, 0, stream>>>(W_qkv, wtq, DD, ND3);
        int no = DD * DD;
        transpose_bf16<<<(no + 255) / 256, 256, 0, stream>>>(W_out, wto, DD, DD);
    }
    qkv_gemm<<<dim3(ND3 / 128, TOK / 128), 256, 0, stream>>>(xb, wtq, b_qkv, qb, kb, vtb);
    attn_kernel<<<dim3(BB * HH, NN / 128), 256, 0, stream>>>(qb, kb, vtb, ao);
    out_gemm<<<dim3(DD / 128, TOK / 128), 256, 0, stream>>>(ao, wto, b_out, out);
}